// Round 13
// baseline (60.143 us; speedup 1.0000x reference)
//
#include <hip/hip_runtime.h>
#include <hip/hip_bf16.h>
#include <math.h>

#define NC 195              // number of countries
#define ROWS_PER_CHUNK 8    // 8 rows * 195 = 1560 floats = 390 float4 = 6240 B
#define CHUNKS 8            // block processes 64 rows
#define BLOCK_ROWS 64
#define F4_PER_CHUNK 390

// ---- DPP butterfly ops within 16-lane rows (VALU pipe; r10-proven) ----
template<int CTRL>
__device__ __forceinline__ float dpp_f(float v) {
    int i = __float_as_int(v);
    return __int_as_float(__builtin_amdgcn_update_dpp(i, i, CTRL, 0xF, 0xF, false));
}
template<int CTRL>
__device__ __forceinline__ int dpp_i(int v) {
    return __builtin_amdgcn_update_dpp(v, v, CTRL, 0xF, 0xF, false);
}

__device__ __forceinline__ float hav_scaled(float lat1, float lon1, float lat2, float lon2) {
    const float d2r = 0.017453292519943295f;
    lat1 *= d2r; lon1 *= d2r; lat2 *= d2r; lon2 *= d2r;
    float sdlat = sinf(0.5f * (lat2 - lat1));
    float sdlon = sinf(0.5f * (lon2 - lon1));
    float a = sdlat * sdlat + cosf(lat1) * cosf(lat2) * sdlon * sdlon;
    a = fminf(fmaxf(a, 0.0f), 1.0f);
    return (2.0f * 6371.0f / 500.0f) * asinf(sqrtf(a));  // 2*R*asin(sqrt(a))/500
}

// Kernel B: 8-row chunks, 32 lanes/row (conflict-free LDS reads: each bank
// exactly 2 lanes per wave read instr), double-buffered LDS (one barrier per
// chunk, writes decoupled from readers), register prefetch of next chunk.
__global__ __launch_bounds__(256) void main_kernel(const float4* __restrict__ logits4,
                                                   const int* __restrict__ target,
                                                   const float* __restrict__ coords,
                                                   float* __restrict__ partials) {
    __shared__ float buf[2][ROWS_PER_CHUNK * NC];   // 2 x 6240 B = 12480 B
    __shared__ int tgt[BLOCK_ROWS];
    __shared__ float wpart[8];
    const int t = threadIdx.x;
    const long long row0 = (long long)blockIdx.x * BLOCK_ROWS;
    if (t < BLOCK_ROWS) tgt[t] = target[row0 + t];   // coalesced 64-int read

    const long long base4 = (row0 >> 2) * NC;        // block's first float4

    // prologue: stage chunk 0 into buf[0]
    float4 a0 = logits4[base4 + t];
    float4 a1;
    if (t < F4_PER_CHUNK - 256) a1 = logits4[base4 + 256 + t];
    {
        float4* d = (float4*)buf[0];
        d[t] = a0;
        if (t < F4_PER_CHUNK - 256) d[256 + t] = a1;
    }
    __syncthreads();

    const int u = t & 31;          // lane within 32-lane row group
    const int g = t >> 5;          // row group (0..7)
    float acc = 0.0f;

    for (int c = 0; c < CHUNKS; ++c) {
        const bool has_next = (c + 1 < CHUNKS);
        if (has_next) {            // issue next chunk's loads under compute
            const long long nb = base4 + (long long)(c + 1) * F4_PER_CHUNK;
            a0 = logits4[nb + t];
            if (t < F4_PER_CHUNK - 256) a1 = logits4[nb + 256 + t];
        }

        const float* __restrict__ rowp = buf[c & 1] + g * NC;
        // conflict-free reads: bank = (3g + u + 32k) % 32; wave = 2 lanes/bank
        float x[7];
        #pragma unroll
        for (int k = 0; k < 6; ++k) x[k] = rowp[u + 32 * k];
        x[6] = (u < 3) ? rowp[192 + u] : -INFINITY;

        // lane-local max + argmax (first occurrence)
        float m = x[0]; int mi = u;
        #pragma unroll
        for (int k = 1; k < 7; ++k) {
            if (x[k] > m) { m = x[k]; mi = u + 32 * k; }
        }
        // butterfly within 16 (DPP), then cross-16 combine (shfl_xor 16)
        {
            float om; int oi;
            om = dpp_f<0xB1>(m);  oi = dpp_i<0xB1>(mi);
            if (om > m || (om == m && oi < mi)) { m = om; mi = oi; }
            om = dpp_f<0x4E>(m);  oi = dpp_i<0x4E>(mi);
            if (om > m || (om == m && oi < mi)) { m = om; mi = oi; }
            om = dpp_f<0x141>(m); oi = dpp_i<0x141>(mi);
            if (om > m || (om == m && oi < mi)) { m = om; mi = oi; }
            om = dpp_f<0x140>(m); oi = dpp_i<0x140>(mi);
            if (om > m || (om == m && oi < mi)) { m = om; mi = oi; }
            om = __shfl_xor(m, 16); oi = __shfl_xor(mi, 16);
            if (om > m || (om == m && oi < mi)) { m = om; mi = oi; }
        }
        float s = 0.0f;
        #pragma unroll
        for (int k = 0; k < 7; ++k) s += __expf(x[k] - m);
        s += dpp_f<0xB1>(s);
        s += dpp_f<0x4E>(s);
        s += dpp_f<0x141>(s);
        s += dpp_f<0x140>(s);
        s += __shfl_xor(s, 16);

        if (u == 0) {
            int tg = tgt[c * ROWS_PER_CHUNK + g];
            float ce = (m + __logf(s)) - rowp[tg];   // lse - x_target (LDS)
            acc += ce + hav_scaled(coords[2 * mi], coords[2 * mi + 1],
                                   coords[2 * tg], coords[2 * tg + 1]);
        }

        if (has_next) {            // write into the OTHER buffer: its previous
            float4* d = (float4*)buf[(c + 1) & 1];   // readers finished before the
            d[t] = a0;                               // barrier that ended it(c-1)
            if (t < F4_PER_CHUNK - 256) d[256 + t] = a1;
        }
        __syncthreads();           // single barrier per chunk
    }

    if (u == 0) wpart[g] = acc;
    __syncthreads();
    if (t == 0) {
        float v = 0.0f;
        #pragma unroll
        for (int j = 0; j < 8; ++j) v += wpart[j];
        partials[blockIdx.x] = v;
    }
}

// Kernel C: single block reduces 4096 partials, writes mean
__global__ __launch_bounds__(1024) void reduce_kernel(const float* __restrict__ partials,
                                                      float inv_b, float* __restrict__ out) {
    float s = partials[threadIdx.x] + partials[threadIdx.x + 1024]
            + partials[threadIdx.x + 2048] + partials[threadIdx.x + 3072];
    #pragma unroll
    for (int off = 32; off > 0; off >>= 1) s += __shfl_xor(s, off);
    __shared__ float ws[16];
    if ((threadIdx.x & 63) == 0) ws[threadIdx.x >> 6] = s;
    __syncthreads();
    if (threadIdx.x == 0) {
        float tot = 0.0f;
        #pragma unroll
        for (int w = 0; w < 16; ++w) tot += ws[w];
        out[0] = tot * inv_b;
    }
}

extern "C" void kernel_launch(void* const* d_in, const int* in_sizes, int n_in,
                              void* d_out, int out_size, void* d_ws, size_t ws_size,
                              hipStream_t stream) {
    const float* logits = (const float*)d_in[0];
    const int*   target = (const int*)d_in[1];
    const float* coords = (const float*)d_in[2];
    float* out = (float*)d_out;

    const int B = in_sizes[1];               // 262144
    const int n_blocks = B / BLOCK_ROWS;     // 4096

    float* partials = (float*)d_ws;          // ws layout: partials[4096]

    main_kernel<<<n_blocks, 256, 0, stream>>>((const float4*)logits, target, coords, partials);
    reduce_kernel<<<1, 1024, 0, stream>>>(partials, 1.0f / (float)B, out);
}

// Round 14
// 43.764 us; speedup vs baseline: 1.3743x; 1.3743x over previous
//
#include <hip/hip_runtime.h>
#include <hip/hip_bf16.h>
#include <math.h>

#define NC 195                 // number of countries
#define ROWS_PER_CHUNK 16      // per-iteration tile: 16 rows = 780 float4 = 12480 B
#define CHUNKS_PER_BLOCK 4     // block processes 64 rows total
#define BLOCK_ROWS (ROWS_PER_CHUNK * CHUNKS_PER_BLOCK)   // 64
#define F4_PER_CHUNK (ROWS_PER_CHUNK * NC / 4)           // 780

// ---- DPP 16-lane butterfly (VALU pipe; r10-proven) ----
template<int CTRL>
__device__ __forceinline__ float dpp_f(float v) {
    int i = __float_as_int(v);
    return __int_as_float(__builtin_amdgcn_update_dpp(i, i, CTRL, 0xF, 0xF, false));
}
template<int CTRL>
__device__ __forceinline__ int dpp_i(int v) {
    return __builtin_amdgcn_update_dpp(v, v, CTRL, 0xF, 0xF, false);
}

__device__ __forceinline__ float hav_scaled(float lat1, float lon1, float lat2, float lon2) {
    const float d2r = 0.017453292519943295f;
    lat1 *= d2r; lon1 *= d2r; lat2 *= d2r; lon2 *= d2r;
    float sdlat = sinf(0.5f * (lat2 - lat1));
    float sdlon = sinf(0.5f * (lon2 - lon1));
    float a = sdlat * sdlat + cosf(lat1) * cosf(lat2) * sdlon * sdlon;
    a = fminf(fmaxf(a, 0.0f), 1.0f);
    return (2.0f * 6371.0f / 500.0f) * asinf(sqrtf(a));  // 2*R*asin(sqrt(a))/500
}

// Kernel B: r10/r11-proven structure (best: 43.8us). 16 rows per chunk staged
// to LDS via float4, register prefetch of next chunk, 16-lane groups with DPP
// butterflies, inline haversine.
__global__ __launch_bounds__(256) void main_kernel(const float4* __restrict__ logits4,
                                                   const int* __restrict__ target,
                                                   const float* __restrict__ coords,
                                                   float* __restrict__ partials) {
    __shared__ float lds[ROWS_PER_CHUNK * NC];   // 12480 B, single buffer
    __shared__ int tgt[BLOCK_ROWS];
    __shared__ float wpart[16];
    const int t = threadIdx.x;
    float4* lds4 = (float4*)lds;

    const long long row0 = (long long)blockIdx.x * BLOCK_ROWS;
    if (t < BLOCK_ROWS) tgt[t] = target[row0 + t];   // one coalesced 64-int read

    const long long base4 = (long long)blockIdx.x * CHUNKS_PER_BLOCK * F4_PER_CHUNK;

    // prologue: stage chunk 0
    float4 n0 = logits4[base4 + t];
    float4 n1 = logits4[base4 + t + 256];
    float4 n2 = logits4[base4 + t + 512];
    float4 n3;
    if (t < F4_PER_CHUNK - 768) n3 = logits4[base4 + t + 768];
    lds4[t] = n0; lds4[t + 256] = n1; lds4[t + 512] = n2;
    if (t < F4_PER_CHUNK - 768) lds4[t + 768] = n3;
    __syncthreads();

    const int u = t & 15;          // lane within 16-lane row group
    const int r = t >> 4;          // row group (0..15)
    const float* __restrict__ rowp = lds + r * NC;
    float acc = 0.0f;

    for (int i = 0; i < CHUNKS_PER_BLOCK; ++i) {
        const bool has_next = (i + 1 < CHUNKS_PER_BLOCK);
        if (has_next) {            // issue next chunk's loads under compute
            const long long nb = base4 + (long long)(i + 1) * F4_PER_CHUNK;
            n0 = logits4[nb + t];
            n1 = logits4[nb + t + 256];
            n2 = logits4[nb + t + 512];
            if (t < F4_PER_CHUNK - 768) n3 = logits4[nb + t + 768];
        }

        float x[13];
        #pragma unroll
        for (int k = 0; k < 12; ++k) x[k] = rowp[u + 16 * k];
        x[12] = (u < 3) ? rowp[192 + u] : -INFINITY;

        // lane-local max + argmax (first occurrence)
        float m = x[0]; int mi = u;
        #pragma unroll
        for (int k = 1; k < 13; ++k) {
            if (x[k] > m) { m = x[k]; mi = u + 16 * k; }
        }
        // DPP butterfly: (max, min-index) over the 16-lane group
        {
            float om; int oi;
            om = dpp_f<0xB1>(m);  oi = dpp_i<0xB1>(mi);
            if (om > m || (om == m && oi < mi)) { m = om; mi = oi; }
            om = dpp_f<0x4E>(m);  oi = dpp_i<0x4E>(mi);
            if (om > m || (om == m && oi < mi)) { m = om; mi = oi; }
            om = dpp_f<0x141>(m); oi = dpp_i<0x141>(mi);
            if (om > m || (om == m && oi < mi)) { m = om; mi = oi; }
            om = dpp_f<0x140>(m); oi = dpp_i<0x140>(mi);
            if (om > m || (om == m && oi < mi)) { m = om; mi = oi; }
        }
        float s = 0.0f;
        #pragma unroll
        for (int k = 0; k < 13; ++k) s += __expf(x[k] - m);
        s += dpp_f<0xB1>(s);
        s += dpp_f<0x4E>(s);
        s += dpp_f<0x141>(s);
        s += dpp_f<0x140>(s);

        if (u == 0) {
            int tg = tgt[i * ROWS_PER_CHUNK + r];
            float ce = (m + __logf(s)) - rowp[tg];   // lse - x_target (LDS)
            acc += ce + hav_scaled(coords[2 * mi], coords[2 * mi + 1],
                                   coords[2 * tg], coords[2 * tg + 1]);
        }
        __syncthreads();                // all groups done reading chunk i
        if (has_next) {
            lds4[t] = n0; lds4[t + 256] = n1; lds4[t + 512] = n2;
            if (t < F4_PER_CHUNK - 768) lds4[t + 768] = n3;
            __syncthreads();            // chunk i+1 visible
        }
    }

    if (u == 0) wpart[r] = acc;
    __syncthreads();
    if (t == 0) {
        float v = 0.0f;
        #pragma unroll
        for (int j = 0; j < 16; ++j) v += wpart[j];
        partials[blockIdx.x] = v;
    }
}

// Kernel C: single block reduces 4096 partials, writes mean
__global__ __launch_bounds__(1024) void reduce_kernel(const float* __restrict__ partials,
                                                      float inv_b, float* __restrict__ out) {
    float s = partials[threadIdx.x] + partials[threadIdx.x + 1024]
            + partials[threadIdx.x + 2048] + partials[threadIdx.x + 3072];
    #pragma unroll
    for (int off = 32; off > 0; off >>= 1) s += __shfl_xor(s, off);
    __shared__ float ws[16];
    if ((threadIdx.x & 63) == 0) ws[threadIdx.x >> 6] = s;
    __syncthreads();
    if (threadIdx.x == 0) {
        float tot = 0.0f;
        #pragma unroll
        for (int w = 0; w < 16; ++w) tot += ws[w];
        out[0] = tot * inv_b;
    }
}

extern "C" void kernel_launch(void* const* d_in, const int* in_sizes, int n_in,
                              void* d_out, int out_size, void* d_ws, size_t ws_size,
                              hipStream_t stream) {
    const float* logits = (const float*)d_in[0];
    const int*   target = (const int*)d_in[1];
    const float* coords = (const float*)d_in[2];
    float* out = (float*)d_out;

    const int B = in_sizes[1];               // 262144
    const int n_blocks = B / BLOCK_ROWS;     // 4096

    float* partials = (float*)d_ws;          // ws layout: partials[4096]

    main_kernel<<<n_blocks, 256, 0, stream>>>((const float4*)logits, target, coords, partials);
    reduce_kernel<<<1, 1024, 0, stream>>>(partials, 1.0f / (float)B, out);
}